// Round 3
// baseline (7615.673 us; speedup 1.0000x reference)
//
#include <hip/hip_runtime.h>
#include <stddef.h>
#include <stdint.h>

// Problem dims (fixed by the reference)
#define BB 32
#define TT 2048
#define NI 128
#define NH 512
#define NO 128

// d_out layout (floats): z[BB*NO] | X[BB*TT*NH] | As[BB*TT*NH] | Phis[BB*TT*NH]
#define Z_OFS   0
#define X_OFS   (BB * NO)
#define AS_OFS  (X_OFS + (size_t)BB * TT * NH)
#define PHI_OFS (AS_OFS + (size_t)BB * TT * NH)

// Scan decomposition: 4 WGs per batch, each owns a 128-row h-slice of Wr
// pinned in VGPRs (64 f32/thread @ 1024 threads). Per-step state exchange
// via global xbuf + per-(step,producer) release/acquire flags.
// Grid mapping wg = j*BB + b keeps all 4 WGs of a batch on one XCD under
// the %8 round-robin heuristic (sync resolves in local L2 when it holds;
// agent scope keeps it correct when it doesn't).
#define WGPB 4
#define HSL  (NH / WGPB)   // 128 h per WG
#define NG   8             // k-groups per WG
#define KG   (NH / NG)     // 64 k per group
#define NTHR 1024

// d_ws layout (bytes):
//   xbuf : [2][BB][NH] f32                      = 131072 B
//   flags: [TT][BB][WGPB] u32, 64B stride/slot  = TT*BB*WGPB*64... too big;
//          per-batch flags: flag(t,b,j) at ((t*BB+b)*WGPB+j)*16 u32 (64B apart)
#define XBUF_BYTES  (2 * BB * NH * 4)
#define FLAG_STRIDE 16  // u32s between slots = 64 B
#define FLAG_WORDS  ((size_t)TT * BB * WGPB * FLAG_STRIDE)

// ---------------------------------------------------------------------------
// Kernel 1: ui[bt][h] = sum_k u[bt][k] * Wi[h][k]   (written into As region)
// ---------------------------------------------------------------------------
__global__ void __launch_bounds__(256) ui_gemm(const float* __restrict__ u,
                                               const float* __restrict__ Wi,
                                               float* __restrict__ ui_out) {
    __shared__ float Au[64][NI + 1];
    __shared__ float Bw[64][NI + 1];
    const int tid = threadIdx.x;
    const int bt0 = blockIdx.x * 64;
    const int h0  = blockIdx.y * 64;

    for (int idx = tid; idx < 64 * (NI / 4); idx += 256) {
        const int r = idx >> 5;
        const int c = (idx & 31) << 2;
        float4 va = *reinterpret_cast<const float4*>(&u[(size_t)(bt0 + r) * NI + c]);
        Au[r][c + 0] = va.x; Au[r][c + 1] = va.y; Au[r][c + 2] = va.z; Au[r][c + 3] = va.w;
        float4 vb = *reinterpret_cast<const float4*>(&Wi[(size_t)(h0 + r) * NI + c]);
        Bw[r][c + 0] = vb.x; Bw[r][c + 1] = vb.y; Bw[r][c + 2] = vb.z; Bw[r][c + 3] = vb.w;
    }
    __syncthreads();

    const int tx = tid & 15;
    const int ty = tid >> 4;
    float acc[4][4] = {};
    for (int k = 0; k < NI; ++k) {
        float a_[4], b_[4];
#pragma unroll
        for (int i = 0; i < 4; ++i) a_[i] = Au[ty * 4 + i][k];
#pragma unroll
        for (int j = 0; j < 4; ++j) b_[j] = Bw[tx * 4 + j][k];
#pragma unroll
        for (int i = 0; i < 4; ++i)
#pragma unroll
            for (int j = 0; j < 4; ++j) acc[i][j] += a_[i] * b_[j];
    }
#pragma unroll
    for (int i = 0; i < 4; ++i)
#pragma unroll
        for (int j = 0; j < 4; ++j)
            ui_out[(size_t)(bt0 + ty * 4 + i) * NH + (h0 + tx * 4 + j)] = acc[i][j];
}

// ---------------------------------------------------------------------------
// Kernel 2: multi-WG scan with VGPR-pinned weights and flag-based sync.
// ---------------------------------------------------------------------------
__global__ void __launch_bounds__(NTHR) rnn_scan_mw(const float* __restrict__ Wr,
                                                    float* __restrict__ out,
                                                    float* __restrict__ xbuf,
                                                    unsigned int* __restrict__ flags) {
    const int wg  = blockIdx.x;       // 0..127
    const int b   = wg % BB;          // all j-slices of batch b share blockIdx%8
    const int j   = wg / BB;
    const int h0  = j * HSL;
    const int tid = threadIdx.x;
    const int hh  = tid & (HSL - 1);  // h within slice
    const int g   = tid >> 7;         // k-group 0..7

    __shared__ float x_lds[NH];
    __shared__ float part[NG][HSL];

    // --- Weight stripe: Wr[h0+hh][g*64 .. g*64+63] -> 64 VGPRs, PINNED.
    float4 w[16];
    {
        const float* wrow = Wr + (size_t)(h0 + hh) * NH + g * KG;
#pragma unroll
        for (int i = 0; i < 16; ++i)
            w[i] = reinterpret_cast<const float4*>(wrow)[i];
        // Opaque asm: values now "originate" here -> loads cannot be
        // rematerialized inside the loop (the R2 failure mode, VGPR=48).
#pragma unroll
        for (int i = 0; i < 16; ++i)
            asm volatile("" : "+v"(w[i].x), "+v"(w[i].y), "+v"(w[i].z), "+v"(w[i].w));
    }

    float* __restrict__ Xp  = out + X_OFS   + (size_t)b * TT * NH;
    float* __restrict__ Asp = out + AS_OFS  + (size_t)b * TT * NH;
    float* __restrict__ Php = out + PHI_OFS + (size_t)b * TT * NH;
    unsigned int* __restrict__ bflag = flags + (size_t)b * WGPB * FLAG_STRIDE;

    if (tid < NH) x_lds[tid] = 0.0f;   // x0 = 0 (visible after first barrier)

    // ui prefetch for t=0
    float uival = 0.0f;
    if (tid < HSL) uival = Asp[h0 + hh];

    for (int t = 0; t < TT; ++t) {
        const size_t o = (size_t)t * NH + h0 + hh;   // meaningful for tid < HSL

        // stage remote x_t slices (own slice written locally last step)
        if (tid < NH && (tid >> 7) != j) {
            x_lds[tid] = xbuf[((size_t)(t & 1) * BB + b) * NH + tid];
        }
        __syncthreads();

        // dot: a_partial[h0+hh] over k in [g*64, g*64+64)
        float acc = 0.0f;
#pragma unroll
        for (int i = 0; i < 16; ++i) {
            float4 xv = *reinterpret_cast<const float4*>(&x_lds[g * KG + 4 * i]);
            acc += w[i].x * xv.x + w[i].y * xv.y + w[i].z * xv.z + w[i].w * xv.w;
        }
        part[g][hh] = acc;
        __syncthreads();

        float a = 0.0f, phi = 0.0f;
        if (tid < HSL) {
            a = uival;
#pragma unroll
            for (int gg = 0; gg < NG; ++gg) a += part[gg][tid];
            phi = tanhf(a);
            x_lds[h0 + tid] = phi;                                  // local copy
            xbuf[((size_t)((t + 1) & 1) * BB + b) * NH + h0 + tid] = phi;
        }
        __syncthreads();   // drains xbuf stores (vmcnt0 before s_barrier)

        if (tid == 0) {
            __hip_atomic_store(&bflag[((size_t)t * BB * WGPB + j) * FLAG_STRIDE],
                               1u, __ATOMIC_RELEASE, __HIP_MEMORY_SCOPE_AGENT);
        }

        // ---- shadow of flag propagation: output streaming + next ui prefetch
        if (tid < HSL) {
            Asp[o] = a;
            Xp [o] = phi;
            Php[o] = phi;
            if (t + 1 < TT) uival = Asp[o + NH];
        }

        // wait for the other 3 producers of this batch
        if (tid < WGPB && tid != j) {
            while (__hip_atomic_load(
                       &bflag[((size_t)t * BB * WGPB + tid) * FLAG_STRIDE],
                       __ATOMIC_RELAXED, __HIP_MEMORY_SCOPE_AGENT) == 0u) { }
        }
        if (tid < 64) __builtin_amdgcn_fence(__ATOMIC_ACQUIRE, "agent");
        __syncthreads();
    }
}

// ---------------------------------------------------------------------------
// Kernel 3: z[b][o] = sum_h X[b][T-1][h] * Wo[o][h]
// ---------------------------------------------------------------------------
__global__ void __launch_bounds__(128) z_gemv(const float* __restrict__ Wo,
                                              float* __restrict__ out) {
    const int b = blockIdx.x;
    const int o = threadIdx.x;
    __shared__ float xl[NH];
    const float* Xlast = out + X_OFS + (size_t)b * TT * NH + (size_t)(TT - 1) * NH;
    for (int h = threadIdx.x; h < NH; h += 128) xl[h] = Xlast[h];
    __syncthreads();
    float acc = 0.f;
#pragma unroll 4
    for (int h4 = 0; h4 < NH / 4; ++h4) {
        float4 w = *reinterpret_cast<const float4*>(&Wo[(size_t)o * NH + h4 * 4]);
        acc += xl[h4 * 4 + 0] * w.x + xl[h4 * 4 + 1] * w.y +
               xl[h4 * 4 + 2] * w.z + xl[h4 * 4 + 3] * w.w;
    }
    out[Z_OFS + (size_t)b * NO + o] = acc;
}

// ---------------------------------------------------------------------------
extern "C" void kernel_launch(void* const* d_in, const int* in_sizes, int n_in,
                              void* d_out, int out_size, void* d_ws, size_t ws_size,
                              hipStream_t stream) {
    const float* u  = (const float*)d_in[0];
    const float* Wr = (const float*)d_in[1];
    const float* Wi = (const float*)d_in[2];
    const float* Wo = (const float*)d_in[3];
    float* out = (float*)d_out;

    float*        xbuf  = (float*)d_ws;
    unsigned int* flags = (unsigned int*)((char*)d_ws + XBUF_BYTES);

    // zero xbuf (x0 = 0) and all flags — required every replay (no re-poison)
    hipMemsetAsync(d_ws, 0, XBUF_BYTES + FLAG_WORDS * 4, stream);

    // ui -> As region of d_out (scan reads it there, then overwrites with a)
    ui_gemm<<<dim3((BB * TT) / 64, NH / 64), 256, 0, stream>>>(u, Wi, out + AS_OFS);

    rnn_scan_mw<<<BB * WGPB, NTHR, 0, stream>>>(Wr, out, xbuf, flags);

    z_gemv<<<BB, 128, 0, stream>>>(Wo, out);
}